// Round 1
// baseline (970.201 us; speedup 1.0000x reference)
//
#include <hip/hip_runtime.h>
#include <cstdint>

#define D_MODEL 1024
#define N_EXP   16
#define D_FF    4096
#define NTOK    4096      // B*T
#define NSEL    8192      // NTOK * k

typedef uint16_t u16;
typedef __bf16    bf16x8 __attribute__((ext_vector_type(8)));
typedef uint16_t  u16x8  __attribute__((ext_vector_type(8)));
typedef float     f32x4  __attribute__((ext_vector_type(4)));
typedef uint32_t  u32x2  __attribute__((ext_vector_type(2)));

__device__ __forceinline__ u16 f2bf(float x) {
    union { float f; uint32_t i; } c; c.f = x;
    uint32_t i = c.i + 0x7fffu + ((c.i >> 16) & 1u);   // RNE (finite data)
    return (u16)(i >> 16);
}

// packed f32x2 -> bf16x2 (RNE), 1 instruction for 2 elements
__device__ __forceinline__ uint32_t cvtpk(float lo, float hi) {
    uint32_t r;
    asm("v_cvt_pk_bf16_f32 %0, %1, %2" : "=v"(r) : "v"(lo), "v"(hi));
    return r;
}

// async global->LDS, 16B per lane; lds base must be wave-uniform
#define ASYNC16(gp, lp) __builtin_amdgcn_global_load_lds( \
    (__attribute__((address_space(1))) void*)(gp),        \
    (__attribute__((address_space(3))) void*)(lp), 16, 0, 0)

// ---------------- gating: one wave per token, exact fp32 ----------------
__global__ void gate_kernel(const float* __restrict__ x, const float* __restrict__ Wg,
                            int* __restrict__ tok_idx, float* __restrict__ tok_w,
                            int* __restrict__ counts)
{
    const int lane = threadIdx.x & 63;
    const int t = blockIdx.x * 4 + (threadIdx.x >> 6);
    const float* xr = x + (size_t)t * D_MODEL;
    float acc[N_EXP];
    #pragma unroll
    for (int e = 0; e < N_EXP; e++) acc[e] = 0.f;
    for (int d = lane; d < D_MODEL; d += 64) {
        float xv = xr[d];
        const float* wr = Wg + d * N_EXP;
        #pragma unroll
        for (int e = 0; e < N_EXP; e++) acc[e] += xv * wr[e];
    }
    #pragma unroll
    for (int e = 0; e < N_EXP; e++) {
        float v = acc[e];
        #pragma unroll
        for (int o = 32; o > 0; o >>= 1) v += __shfl_xor(v, o, 64);
        acc[e] = v;
    }
    if (lane == 0) {
        int i0 = 0; float v0 = acc[0];
        #pragma unroll
        for (int e = 1; e < N_EXP; e++) if (acc[e] > v0) { v0 = acc[e]; i0 = e; }
        int i1 = (i0 == 0) ? 1 : 0; float v1 = -3.0e38f;
        #pragma unroll
        for (int e = 0; e < N_EXP; e++) if (e != i0 && acc[e] > v1) { v1 = acc[e]; i1 = e; }
        float e1  = __expf(v1 - v0);
        float inv = 1.f / (1.f + e1);
        tok_idx[2 * t] = i0;  tok_idx[2 * t + 1] = i1;
        tok_w[2 * t] = inv;   tok_w[2 * t + 1] = e1 * inv;
        atomicAdd(&counts[i0], 1);
        atomicAdd(&counts[i1], 1);
    }
}

__global__ void scan_kernel(const int* __restrict__ counts, int* __restrict__ offsets,
                            int* __restrict__ cursors)
{
    if (threadIdx.x == 0) {
        int s = 0;
        #pragma unroll
        for (int e = 0; e < N_EXP; e++) { offsets[e] = s; cursors[e] = s; s += counts[e]; }
        offsets[N_EXP] = s;   // == NSEL
    }
}

__global__ void scatter_kernel(const int* __restrict__ tok_idx, const float* __restrict__ tok_w,
                               int* __restrict__ cursors, int* __restrict__ perm_token,
                               float* __restrict__ perm_w, int* __restrict__ slots)
{
    const int t = blockIdx.x * 256 + threadIdx.x;
    #pragma unroll
    for (int j = 0; j < 2; j++) {
        int e = tok_idx[2 * t + j];
        int slot = atomicAdd(&cursors[e], 1);
        perm_token[slot] = t;
        perm_w[slot] = tok_w[2 * t + j];
        slots[2 * t + j] = slot;
    }
}

// ---------------- gather + fp32->bf16 convert of A (x permuted) ----------------
// One block per slot: 256 lanes x 4 floats = 1024 = D_MODEL.
__global__ void gatherA_kernel(const float* __restrict__ x, const int* __restrict__ perm_token,
                               u16* __restrict__ Abf)
{
    const int slot = blockIdx.x;
    const int t = perm_token[slot];
    const float* src = x + (size_t)t * D_MODEL;
    u16* dst = Abf + (size_t)slot * D_MODEL;
    const int d = threadIdx.x * 4;
    f32x4 v = *(const f32x4*)(src + d);
    u32x2 o;
    o.x = cvtpk(v[0], v[1]);
    o.y = cvtpk(v[2], v[3]);
    *(u32x2*)(dst + d) = o;
}

// ---------------- grouped GEMM, 128x128 tile, BK=32, 4 waves ----------------
// A: bf16 [row][K], staged via global_load_lds width=16 with SOURCE-side octet
//    swizzle (LDS dest linear).
// B: fp32 [e][K][N] k-major; k-pair loads + v_cvt_pk_bf16_f32 -> transposed
//    [n][k] LDS tile with XOR octet swizzle, 8x ds_write_b32 per thread.
// Swizzle (both tiles): k-octet position = octet ^ ((row>>1)&3) ^ ((row>>3)&3).
// Fragment ds_read_b128 is bank-even (2-way only = free, m136).
template<bool SWISH>
__global__ __launch_bounds__(256, 3)
void gemm_kernel(const u16* __restrict__ A, const float* __restrict__ W,
                 const float* __restrict__ bias, const int* __restrict__ offsets,
                 const float* __restrict__ perm_w,
                 u16* __restrict__ Hout, float* __restrict__ Yout,
                 int K, int N)
{
    const int e   = blockIdx.z;
    const int off = offsets[e];
    const int cnt = offsets[e + 1] - off;
    const int m0  = blockIdx.y * 128;
    if (m0 >= cnt) return;
    const int n0  = blockIdx.x * 128;

    __shared__ u16 Alds[128 * 32];   // [m][k], octet-swizzled via source
    __shared__ u16 Blds[128 * 32];   // [n][k] transposed, octet-swizzled

    const int tid  = threadIdx.x;
    const int lane = tid & 63;
    const int w    = tid >> 6;
    const int wm   = w & 1;
    const int wn   = w >> 1;

    // --- A staging: lane covers LDS row w*16+(lane>>2), octet slot lane&3 ---
    const int arow = w * 16 + (lane >> 2);
    const int oA   = (lane & 3) ^ ((arow >> 1) & 3) ^ ((arow >> 3) & 3);
    int rA = m0 + arow;      if (rA > cnt - 1) rA = cnt - 1;
    int rB = m0 + arow + 64; if (rB > cnt - 1) rB = cnt - 1;   // swz(r+64)==swz(r)
    const u16* aph0 = A + (size_t)(off + rA) * K + oA * 8;
    const u16* aph1 = A + (size_t)(off + rB) * K + oA * 8;

    // --- B staging: thread (fo, dp) handles k rows 2dp,2dp+1, n cols fo*8..+7 ---
    const int fo = tid & 15;
    const int dp = tid >> 4;
    const int k0 = 2 * dp;
    const float* bbase = W + (size_t)e * K * N + n0 + fo * 8;
    const int koct = dp >> 2;
    const int kin  = k0 & 7;          // even -> u32-aligned
    uint32_t* bwp[8];
    #pragma unroll
    for (int j = 0; j < 8; j++) {
        const int row = fo * 8 + j;
        const int oct = koct ^ (fo & 3) ^ ((j >> 1) & 3);  // == koct ^ swz(row)
        bwp[j] = (uint32_t*)&Blds[row * 32 + oct * 8 + kin];
    }

    // --- fragment read offsets (swizzled) ---
    const int q = lane >> 4;
    int a_rd[4];
    #pragma unroll
    for (int mi = 0; mi < 4; mi++) {
        const int r   = wm * 64 + mi * 16 + (lane & 15);
        const int oct = q ^ ((r >> 1) & 3) ^ ((r >> 3) & 3);
        a_rd[mi] = r * 32 + oct * 8;
    }
    const int fbase = wn * 64 + (lane & 15);
    int b_rd[4];
    #pragma unroll
    for (int ni = 0; ni < 4; ni++) {
        const int f   = fbase + ni * 16;
        const int oct = q ^ ((f >> 1) & 3) ^ ((f >> 3) & 3);
        b_rd[ni] = f * 32 + oct * 8;
    }

    f32x4 acc[4][4] = {};

    for (int kt = 0; kt < K; kt += 32) {
        // A tile: async, zero VALU
        ASYNC16(aph0 + kt, &Alds[w * 512]);
        ASYNC16(aph1 + kt, &Alds[(w + 4) * 512]);
        // B tile: k-pair convert + transpose
        {
            const float* bp = bbase + (size_t)kt * N;
            f32x4 w00 = *(const f32x4*)(bp + (size_t)k0 * N);
            f32x4 w01 = *(const f32x4*)(bp + (size_t)k0 * N + 4);
            f32x4 w10 = *(const f32x4*)(bp + (size_t)(k0 + 1) * N);
            f32x4 w11 = *(const f32x4*)(bp + (size_t)(k0 + 1) * N + 4);
            #pragma unroll
            for (int j = 0; j < 4; j++) *bwp[j]     = cvtpk(w00[j], w10[j]);
            #pragma unroll
            for (int j = 0; j < 4; j++) *bwp[4 + j] = cvtpk(w01[j], w11[j]);
        }
        __syncthreads();   // drains vmcnt+lgkmcnt (compiler-inserted)

        u16x8 af[4], bfr[4];
        #pragma unroll
        for (int mi = 0; mi < 4; mi++) af[mi] = *(const u16x8*)(&Alds[a_rd[mi]]);
        #pragma unroll
        for (int ni = 0; ni < 4; ni++) bfr[ni] = *(const u16x8*)(&Blds[b_rd[ni]]);
        #pragma unroll
        for (int mi = 0; mi < 4; mi++)
            #pragma unroll
            for (int ni = 0; ni < 4; ni++)
                acc[mi][ni] = __builtin_amdgcn_mfma_f32_16x16x32_bf16(
                    __builtin_bit_cast(bf16x8, af[mi]),
                    __builtin_bit_cast(bf16x8, bfr[ni]),
                    acc[mi][ni], 0, 0, 0);
        __syncthreads();
    }

    // epilogue: C/D layout col=lane&15, row=(lane>>4)*4+reg  [m89-verified]
    const int rowq = (lane >> 4) * 4;
    #pragma unroll
    for (int mi = 0; mi < 4; mi++) {
        #pragma unroll
        for (int r = 0; r < 4; r++) {
            const int m = m0 + wm * 64 + mi * 16 + rowq + r;
            if (m < cnt) {
                const size_t gm = (size_t)(off + m);
                float pw = SWISH ? 0.f : perm_w[gm];
                #pragma unroll
                for (int ni = 0; ni < 4; ni++) {
                    const int gn = n0 + fbase + ni * 16;
                    float c = acc[mi][ni][r] + bias[(size_t)e * N + gn];
                    if (SWISH) {
                        float s = c / (1.f + __expf(-c));   // swish
                        Hout[gm * (size_t)N + gn] = f2bf(s);
                    } else {
                        Yout[gm * (size_t)N + gn] = c * pw;
                    }
                }
            }
        }
    }
}

// ---------------- combine: out[t] = Y[slot0] + Y[slot1] (fp32 out) ----------------
__global__ void combine_kernel(const float* __restrict__ Y, const int* __restrict__ slots,
                               float* __restrict__ out)
{
    const int idx = blockIdx.x * 256 + threadIdx.x;
    const int t = idx >> 8;
    const int d = (idx & 255) * 4;
    const int s0 = slots[2 * t], s1 = slots[2 * t + 1];
    f32x4 a = *(const f32x4*)(Y + (size_t)s0 * D_MODEL + d);
    f32x4 b = *(const f32x4*)(Y + (size_t)s1 * D_MODEL + d);
    f32x4 o = a + b;
    *(f32x4*)(out + (size_t)t * D_MODEL + d) = o;
}

extern "C" void kernel_launch(void* const* d_in, const int* in_sizes, int n_in,
                              void* d_out, int out_size, void* d_ws, size_t ws_size,
                              hipStream_t stream)
{
    const float* x  = (const float*)d_in[0];
    const float* W1 = (const float*)d_in[1];
    const float* b1 = (const float*)d_in[2];
    const float* W2 = (const float*)d_in[3];
    const float* b2 = (const float*)d_in[4];
    const float* Wg = (const float*)d_in[5];
    // d_in[6] = k (always 2)

    char* ws = (char*)d_ws;
    int*   counts     = (int*)(ws);                      // 64 B
    int*   offsets    = (int*)(ws + 64);                 // 17 ints
    int*   cursors    = (int*)(ws + 192);                // 16 ints
    int*   tok_idx    = (int*)(ws + 256);                // 8192 ints
    float* tok_w      = (float*)(ws + 256 + 32768);      // 8192 f32
    int*   slots      = (int*)(ws + 256 + 2 * 32768);    // 8192 ints
    int*   perm_token = (int*)(ws + 256 + 3 * 32768);    // 8192 ints
    float* perm_w     = (float*)(ws + 256 + 4 * 32768);  // 8192 f32
    u16*   h          = (u16*)(ws + 262144);                             // 64 MB bf16
    float* Yslot      = (float*)(ws + 262144 + (size_t)NSEL * D_FF * 2); // 32 MB f32
    // Abf (16 MB, bf16 gathered x) ALIASES Yslot: dead before GEMM2 writes Yslot.
    u16*   Abf        = (u16*)Yslot;
    // total ws needed ~= 96.3 MiB (unchanged)

    hipMemsetAsync(counts, 0, 64, stream);
    gate_kernel<<<dim3(NTOK / 4), dim3(256), 0, stream>>>(x, Wg, tok_idx, tok_w, counts);
    scan_kernel<<<dim3(1), dim3(64), 0, stream>>>(counts, offsets, cursors);
    scatter_kernel<<<dim3(NTOK / 256), dim3(256), 0, stream>>>(tok_idx, tok_w, cursors,
                                                               perm_token, perm_w, slots);
    gatherA_kernel<<<dim3(NSEL), dim3(256), 0, stream>>>(x, perm_token, Abf);
    gemm_kernel<true><<<dim3(32, 32, 16), dim3(256), 0, stream>>>(
        Abf, W1, b1, offsets, nullptr, h, nullptr, D_MODEL, D_FF);
    gemm_kernel<false><<<dim3(8, 32, 16), dim3(256), 0, stream>>>(
        (const u16*)h, W2, b2, offsets, perm_w, nullptr, Yslot, D_FF, D_MODEL);
    combine_kernel<<<dim3(NTOK), dim3(256), 0, stream>>>(Yslot, slots, (float*)d_out);
}

// Round 2
// 942.459 us; speedup vs baseline: 1.0294x; 1.0294x over previous
//
#include <hip/hip_runtime.h>
#include <cstdint>

#define D_MODEL 1024
#define N_EXP   16
#define D_FF    4096
#define NTOK    4096      // B*T
#define NSEL    8192      // NTOK * k

typedef uint16_t u16;
typedef __bf16    bf16x8 __attribute__((ext_vector_type(8)));
typedef uint16_t  u16x8  __attribute__((ext_vector_type(8)));
typedef float     f32x4  __attribute__((ext_vector_type(4)));
typedef uint32_t  u32x2  __attribute__((ext_vector_type(2)));

__device__ __forceinline__ u16 f2bf(float x) {
    union { float f; uint32_t i; } c; c.f = x;
    uint32_t i = c.i + 0x7fffu + ((c.i >> 16) & 1u);   // RNE (finite data)
    return (u16)(i >> 16);
}

// packed f32x2 -> bf16x2 (RNE), 1 instruction for 2 elements
__device__ __forceinline__ uint32_t cvtpk(float lo, float hi) {
    uint32_t r;
    asm("v_cvt_pk_bf16_f32 %0, %1, %2" : "=v"(r) : "v"(lo), "v"(hi));
    return r;
}

// async global->LDS, 16B per lane; lds base must be wave-uniform
#define ASYNC16(gp, lp) __builtin_amdgcn_global_load_lds( \
    (__attribute__((address_space(1))) void*)(gp),        \
    (__attribute__((address_space(3))) void*)(lp), 16, 0, 0)

// ---------------- gating: one wave per token, exact fp32 ----------------
__global__ void gate_kernel(const float* __restrict__ x, const float* __restrict__ Wg,
                            int* __restrict__ tok_idx, float* __restrict__ tok_w,
                            int* __restrict__ counts)
{
    const int lane = threadIdx.x & 63;
    const int t = blockIdx.x * 4 + (threadIdx.x >> 6);
    const float* xr = x + (size_t)t * D_MODEL;
    float acc[N_EXP];
    #pragma unroll
    for (int e = 0; e < N_EXP; e++) acc[e] = 0.f;
    for (int d = lane; d < D_MODEL; d += 64) {
        float xv = xr[d];
        const float* wr = Wg + d * N_EXP;
        #pragma unroll
        for (int e = 0; e < N_EXP; e++) acc[e] += xv * wr[e];
    }
    #pragma unroll
    for (int e = 0; e < N_EXP; e++) {
        float v = acc[e];
        #pragma unroll
        for (int o = 32; o > 0; o >>= 1) v += __shfl_xor(v, o, 64);
        acc[e] = v;
    }
    if (lane == 0) {
        int i0 = 0; float v0 = acc[0];
        #pragma unroll
        for (int e = 1; e < N_EXP; e++) if (acc[e] > v0) { v0 = acc[e]; i0 = e; }
        int i1 = (i0 == 0) ? 1 : 0; float v1 = -3.0e38f;
        #pragma unroll
        for (int e = 0; e < N_EXP; e++) if (e != i0 && acc[e] > v1) { v1 = acc[e]; i1 = e; }
        float e1  = __expf(v1 - v0);
        float inv = 1.f / (1.f + e1);
        tok_idx[2 * t] = i0;  tok_idx[2 * t + 1] = i1;
        tok_w[2 * t] = inv;   tok_w[2 * t + 1] = e1 * inv;
        atomicAdd(&counts[i0], 1);
        atomicAdd(&counts[i1], 1);
    }
}

__global__ void scan_kernel(const int* __restrict__ counts, int* __restrict__ offsets,
                            int* __restrict__ cursors)
{
    if (threadIdx.x == 0) {
        int s = 0;
        #pragma unroll
        for (int e = 0; e < N_EXP; e++) { offsets[e] = s; cursors[e] = s; s += counts[e]; }
        offsets[N_EXP] = s;   // == NSEL
    }
}

__global__ void scatter_kernel(const int* __restrict__ tok_idx, const float* __restrict__ tok_w,
                               int* __restrict__ cursors, int* __restrict__ perm_token,
                               float* __restrict__ perm_w)
{
    const int t = blockIdx.x * 256 + threadIdx.x;
    #pragma unroll
    for (int j = 0; j < 2; j++) {
        int e = tok_idx[2 * t + j];
        int slot = atomicAdd(&cursors[e], 1);
        perm_token[slot] = t;
        perm_w[slot] = tok_w[2 * t + j];
    }
}

// ---------------- gather + fp32->bf16 convert of A (x permuted) ----------------
__global__ void gatherA_kernel(const float* __restrict__ x, const int* __restrict__ perm_token,
                               u16* __restrict__ Abf)
{
    const int slot = blockIdx.x;
    const int t = perm_token[slot];
    const float* src = x + (size_t)t * D_MODEL;
    u16* dst = Abf + (size_t)slot * D_MODEL;
    const int d = threadIdx.x * 4;
    f32x4 v = *(const f32x4*)(src + d);
    u32x2 o;
    o.x = cvtpk(v[0], v[1]);
    o.y = cvtpk(v[2], v[3]);
    *(u32x2*)(dst + d) = o;
}

// ---------------- grouped GEMM, 128x128 tile, BK=32, 4 waves, 2-phase dbuf ----
// A: bf16 [row][K] via global_load_lds w=16, source-side octet swizzle.
// B: fp32 [e][K][N]; k-pair reg loads + cvt_pk -> [n][k] LDS, octet swizzle.
// Pipeline per K-step: {issue A-async(next) + B-gloads(next)} -> MFMA(cur)
//   -> cvt+ds_write B(next) -> ONE __syncthreads -> swap.  (T3 minimum 2-phase)
// KSPLIT>1 (GEMM2): grid.z = e + 16*ks; fp32 atomicAdd into out[token] fuses
//   the combine kernel (bias added by ks==0 only).
template<bool SWISH, int KSPLIT>
__global__ __launch_bounds__(256, 3)
void gemm_kernel(const u16* __restrict__ A, const float* __restrict__ W,
                 const float* __restrict__ bias, const int* __restrict__ offsets,
                 const int* __restrict__ perm_token, const float* __restrict__ perm_w,
                 u16* __restrict__ Hout, float* __restrict__ Yout,
                 int K, int N)
{
    const int zz  = blockIdx.z;
    const int e   = zz & (N_EXP - 1);
    const int ks  = zz >> 4;
    const int off = offsets[e];
    const int cnt = offsets[e + 1] - off;
    const int m0  = blockIdx.y * 128;
    if (m0 >= cnt) return;
    const int n0  = blockIdx.x * 128;
    const int kbase  = ks * (K / KSPLIT);
    const int ksteps = (K / KSPLIT) / 32;

    __shared__ u16 Alds[2][128 * 32];   // [m][k], octet-swizzled via source
    __shared__ u16 Blds[2][128 * 32];   // [n][k] transposed, octet-swizzled

    const int tid  = threadIdx.x;
    const int lane = tid & 63;
    const int w    = tid >> 6;
    const int wm   = w & 1;
    const int wn   = w >> 1;

    // --- A staging: lane covers LDS row w*16+(lane>>2), octet slot lane&3 ---
    const int arow = w * 16 + (lane >> 2);
    const int oA   = (lane & 3) ^ ((arow >> 1) & 3) ^ ((arow >> 3) & 3);
    int rA = m0 + arow;      if (rA > cnt - 1) rA = cnt - 1;
    int rB = m0 + arow + 64; if (rB > cnt - 1) rB = cnt - 1;   // swz(r+64)==swz(r)
    const u16* aph0 = A + (size_t)(off + rA) * K + oA * 8;
    const u16* aph1 = A + (size_t)(off + rB) * K + oA * 8;

    // --- B staging: thread (fo, dp) handles k rows 2dp,2dp+1, n cols fo*8..+7 ---
    const int fo = tid & 15;
    const int dp = tid >> 4;
    const int k0 = 2 * dp;
    const float* bbase = W + (size_t)e * K * N + n0 + fo * 8;
    const int koct = dp >> 2;
    const int kin  = k0 & 7;          // even -> u32-aligned
    int boff[8];
    #pragma unroll
    for (int j = 0; j < 8; j++) {
        const int row = fo * 8 + j;
        const int oct = koct ^ (fo & 3) ^ ((j >> 1) & 3);  // == koct ^ swz(row)
        boff[j] = row * 32 + oct * 8 + kin;
    }

    // --- fragment read offsets (swizzled) ---
    const int q = lane >> 4;
    int a_rd[4];
    #pragma unroll
    for (int mi = 0; mi < 4; mi++) {
        const int r   = wm * 64 + mi * 16 + (lane & 15);
        const int oct = q ^ ((r >> 1) & 3) ^ ((r >> 3) & 3);
        a_rd[mi] = r * 32 + oct * 8;
    }
    const int fbase = wn * 64 + (lane & 15);
    int b_rd[4];
    #pragma unroll
    for (int ni = 0; ni < 4; ni++) {
        const int f   = fbase + ni * 16;
        const int oct = q ^ ((f >> 1) & 3) ^ ((f >> 3) & 3);
        b_rd[ni] = f * 32 + oct * 8;
    }

    f32x4 acc[4][4] = {};

    // ---- prologue: stage tile 0 into buf 0 ----
    {
        ASYNC16(aph0 + kbase, &Alds[0][w * 512]);
        ASYNC16(aph1 + kbase, &Alds[0][(w + 4) * 512]);
        const float* bp = bbase + (size_t)kbase * N;
        f32x4 w00 = *(const f32x4*)(bp + (size_t)k0 * N);
        f32x4 w01 = *(const f32x4*)(bp + (size_t)k0 * N + 4);
        f32x4 w10 = *(const f32x4*)(bp + (size_t)(k0 + 1) * N);
        f32x4 w11 = *(const f32x4*)(bp + (size_t)(k0 + 1) * N + 4);
        #pragma unroll
        for (int j = 0; j < 4; j++) *(uint32_t*)&Blds[0][boff[j]]     = cvtpk(w00[j], w10[j]);
        #pragma unroll
        for (int j = 0; j < 4; j++) *(uint32_t*)&Blds[0][boff[4 + j]] = cvtpk(w01[j], w11[j]);
    }
    __syncthreads();

    int cur = 0;
    for (int i = 0; i < ksteps; ++i) {
        const bool has_next = (i + 1 < ksteps);
        f32x4 w00, w01, w10, w11;
        if (has_next) {
            const int ktn = kbase + (i + 1) * 32;
            // issue-early: A direct-to-LDS (other buffer), B into registers
            ASYNC16(aph0 + ktn, &Alds[cur ^ 1][w * 512]);
            ASYNC16(aph1 + ktn, &Alds[cur ^ 1][(w + 4) * 512]);
            const float* bp = bbase + (size_t)ktn * N;
            w00 = *(const f32x4*)(bp + (size_t)k0 * N);
            w01 = *(const f32x4*)(bp + (size_t)k0 * N + 4);
            w10 = *(const f32x4*)(bp + (size_t)(k0 + 1) * N);
            w11 = *(const f32x4*)(bp + (size_t)(k0 + 1) * N + 4);
        }

        // compute current buffer
        u16x8 af[4], bfr[4];
        #pragma unroll
        for (int mi = 0; mi < 4; mi++) af[mi] = *(const u16x8*)(&Alds[cur][a_rd[mi]]);
        #pragma unroll
        for (int ni = 0; ni < 4; ni++) bfr[ni] = *(const u16x8*)(&Blds[cur][b_rd[ni]]);
        #pragma unroll
        for (int mi = 0; mi < 4; mi++)
            #pragma unroll
            for (int ni = 0; ni < 4; ni++)
                acc[mi][ni] = __builtin_amdgcn_mfma_f32_16x16x32_bf16(
                    __builtin_bit_cast(bf16x8, af[mi]),
                    __builtin_bit_cast(bf16x8, bfr[ni]),
                    acc[mi][ni], 0, 0, 0);

        if (has_next) {
            // write-late: convert + transpose B(next) after the MFMA block
            #pragma unroll
            for (int j = 0; j < 4; j++) *(uint32_t*)&Blds[cur ^ 1][boff[j]]     = cvtpk(w00[j], w10[j]);
            #pragma unroll
            for (int j = 0; j < 4; j++) *(uint32_t*)&Blds[cur ^ 1][boff[4 + j]] = cvtpk(w01[j], w11[j]);
            __syncthreads();   // one barrier per K-step (drains vmcnt+lgkmcnt)
            cur ^= 1;
        }
    }

    // epilogue: C/D layout col=lane&15, row=(lane>>4)*4+reg  [m89-verified]
    const int rowq = (lane >> 4) * 4;
    #pragma unroll
    for (int mi = 0; mi < 4; mi++) {
        #pragma unroll
        for (int r = 0; r < 4; r++) {
            const int m = m0 + wm * 64 + mi * 16 + rowq + r;
            if (m < cnt) {
                const size_t gm = (size_t)(off + m);
                if constexpr (SWISH) {
                    #pragma unroll
                    for (int ni = 0; ni < 4; ni++) {
                        const int gn = n0 + fbase + ni * 16;
                        float c = acc[mi][ni][r] + bias[(size_t)e * N + gn];
                        float s = c / (1.f + __expf(-c));   // swish
                        Hout[gm * (size_t)N + gn] = f2bf(s);
                    }
                } else {
                    const int   tok = perm_token[gm];
                    const float pw  = perm_w[gm];
                    float* orow = Yout + (size_t)tok * N;
                    #pragma unroll
                    for (int ni = 0; ni < 4; ni++) {
                        const int gn = n0 + fbase + ni * 16;
                        float c = acc[mi][ni][r];
                        if (ks == 0) c += bias[(size_t)e * N + gn];
                        atomicAdd(&orow[gn], c * pw);   // fused combine, split-K sum
                    }
                }
            }
        }
    }
}

extern "C" void kernel_launch(void* const* d_in, const int* in_sizes, int n_in,
                              void* d_out, int out_size, void* d_ws, size_t ws_size,
                              hipStream_t stream)
{
    const float* x  = (const float*)d_in[0];
    const float* W1 = (const float*)d_in[1];
    const float* b1 = (const float*)d_in[2];
    const float* W2 = (const float*)d_in[3];
    const float* b2 = (const float*)d_in[4];
    const float* Wg = (const float*)d_in[5];
    // d_in[6] = k (always 2)

    char* ws = (char*)d_ws;
    int*   counts     = (int*)(ws);                      // 64 B
    int*   offsets    = (int*)(ws + 64);                 // 17 ints
    int*   cursors    = (int*)(ws + 192);                // 16 ints
    int*   tok_idx    = (int*)(ws + 256);                // 8192 ints
    float* tok_w      = (float*)(ws + 256 + 32768);      // 8192 f32
    int*   perm_token = (int*)(ws + 256 + 2 * 32768);    // 8192 ints
    float* perm_w     = (float*)(ws + 256 + 3 * 32768);  // 8192 f32
    u16*   h          = (u16*)(ws + 262144);                          // 64 MB bf16
    u16*   Abf        = (u16*)(ws + 262144 + (size_t)NSEL * D_FF * 2);// 16 MB bf16
    // total ws needed ~= 80.3 MiB

    hipMemsetAsync(counts, 0, 64, stream);
    hipMemsetAsync(d_out, 0, out_size, stream);   // atomic-accumulated output
    gate_kernel<<<dim3(NTOK / 4), dim3(256), 0, stream>>>(x, Wg, tok_idx, tok_w, counts);
    scan_kernel<<<dim3(1), dim3(64), 0, stream>>>(counts, offsets, cursors);
    scatter_kernel<<<dim3(NTOK / 256), dim3(256), 0, stream>>>(tok_idx, tok_w, cursors,
                                                               perm_token, perm_w);
    gatherA_kernel<<<dim3(NSEL), dim3(256), 0, stream>>>(x, perm_token, Abf);
    gemm_kernel<true, 1><<<dim3(32, 32, 16), dim3(256), 0, stream>>>(
        Abf, W1, b1, offsets, nullptr, nullptr, h, nullptr, D_MODEL, D_FF);
    gemm_kernel<false, 4><<<dim3(8, 32, 16 * 4), dim3(256), 0, stream>>>(
        h, W2, b2, offsets, perm_token, perm_w, nullptr, (float*)d_out, D_FF, D_MODEL);
}